// Round 3
// baseline (392.529 us; speedup 1.0000x reference)
//
#include <hip/hip_runtime.h>
#include <hip/hip_bf16.h>

// CrossAttention on MI355X (gfx950). B=4, Nq=Nc=2048, H=8, Dh=64, inner=512,
// Dq=1024, Dc=768, scale=1/8.
//
// ROUND 3: inputs AND output are fp32 (diagnosed from round-2's 0.3857
// absmax == bf16-written-read-as-fp32 signature + round-1 NaN == fp32 read
// as bf16). Internal compute stays bf16 MFMA with fp32 accumulate; the
// final GEMM now writes fp32 when the dtype sniffer says fp32.

typedef __bf16 bf16_8 __attribute__((ext_vector_type(8)));
typedef float f32_4 __attribute__((ext_vector_type(4)));

// ---------------------------------------------------------------------------
// dtype sniffer: fp32 inputs read as uint16 halves show random exponent
// fields (e>=134 for ~48% of low halves); bf16 normals (|v|<8) never do.
__global__ void sniff_dtype(const unsigned short* __restrict__ xb,
                            int* __restrict__ flags) {
  if (blockIdx.x == 0 && threadIdx.x == 0) {
    int cnt = 0;
    for (int i = 0; i < 1024; ++i) {
      const int e = (xb[i] >> 7) & 0xFF;
      cnt += (e >= 134) ? 1 : 0;
    }
    flags[0] = (cnt > 50) ? 1 : 0;  // 1 -> fp32 inputs/outputs
    flags[1] = 0;                   // constant "bf16" flag for ws operands
  }
}

// ---------------------------------------------------------------------------
// Weight transpose + cast: Wt[n*K + k] = (bf16)W[k*N + n].
// grid (N/32, K/32), block 256.
__global__ __launch_bounds__(256) void transpose_w(const void* __restrict__ W,
                                                   __bf16* __restrict__ Wt,
                                                   int K, int N,
                                                   const int* __restrict__ flag) {
  __shared__ __bf16 t[32][33];
  const int fl = flag[0];
  const int k0 = blockIdx.y * 32, n0 = blockIdx.x * 32;
  const int tx = threadIdx.x & 31, ty = threadIdx.x >> 5;  // ty 0..7
  if (fl == 0) {
    const __bf16* Wb = (const __bf16*)W;
#pragma unroll
    for (int r = 0; r < 32; r += 8)
      t[ty + r][tx] = Wb[(size_t)(k0 + ty + r) * N + n0 + tx];
  } else {
    const float* Wf = (const float*)W;
#pragma unroll
    for (int r = 0; r < 32; r += 8)
      t[ty + r][tx] = (__bf16)Wf[(size_t)(k0 + ty + r) * N + n0 + tx];
  }
  __syncthreads();
#pragma unroll
  for (int r = 0; r < 32; r += 8)
    Wt[(size_t)(n0 + ty + r) * K + k0 + tx] = t[tx][ty + r];
}

// ---------------------------------------------------------------------------
// V transpose: Vt[(bh*64 + d)*2048 + j] = V[(b*2048 + j)*512 + h*64 + d]
// grid (2048/64, 32), block 256.  V always bf16 (ws-resident).
__global__ __launch_bounds__(256) void transpose_v(const __bf16* __restrict__ V,
                                                   __bf16* __restrict__ Vt) {
  __shared__ __align__(16) __bf16 t[64][72];
  const int bh = blockIdx.y;
  const int b = bh >> 3, h = bh & 7;
  const int j0 = blockIdx.x * 64;
  const int tr = threadIdx.x >> 3;        // 0..31
  const int tc = (threadIdx.x & 7) * 8;   // 0..56
#pragma unroll
  for (int r = 0; r < 64; r += 32) {
    const int j = j0 + tr + r;
    *(bf16_8*)&t[tr + r][tc] =
        *(const bf16_8*)&V[(size_t)(b * 2048 + j) * 512 + h * 64 + tc];
  }
  __syncthreads();
#pragma unroll
  for (int r = 0; r < 64; r += 32) {
    const int d = tr + r;
    bf16_8 v;
#pragma unroll
    for (int i = 0; i < 8; ++i) v[i] = t[tc + i][d];
    *(bf16_8*)&Vt[((size_t)(bh * 64 + d)) * 2048 + j0 + tc] = v;
  }
}

// ---------------------------------------------------------------------------
// C[M,N] = A[M,K] @ Bt[N,K]^T (+bias), fp32 acc.
// A dtype per aflag (0=bf16, 1=fp32); Bt always bf16; C dtype per oflag.
// grid (N/128, M/128), block 256 (4 waves, 2x2 of 64x64).
__global__ __launch_bounds__(256) void gemm_bt(const void* __restrict__ A,
                                               const __bf16* __restrict__ Bt,
                                               void* __restrict__ C,
                                               int M, int N, int K,
                                               const void* __restrict__ bias,
                                               const int* __restrict__ aflag,
                                               const int* __restrict__ bflag,
                                               const int* __restrict__ oflag) {
  __shared__ __align__(16) __bf16 As[128 * 64];
  __shared__ __align__(16) __bf16 Bs[128 * 64];
  const int afl = aflag[0];
  const int tid = threadIdx.x;
  const int lane = tid & 63;
  const int wave = tid >> 6;
  const int wi = (wave >> 1) * 64;
  const int wn = (wave & 1) * 64;
  const int bm = blockIdx.y * 128;
  const int bn = blockIdx.x * 128;
  const int lrow = lane & 15;
  const int quad = lane >> 4;

  f32_4 acc[4][4];
#pragma unroll
  for (int i = 0; i < 4; ++i)
#pragma unroll
    for (int j = 0; j < 4; ++j)
#pragma unroll
      for (int r = 0; r < 4; ++r) acc[i][j][r] = 0.0f;

  const int srow = tid >> 3;        // 0..31
  const int scol = (tid & 7) * 8;   // 0..56
  const __bf16* Ab = (const __bf16*)A;
  const float*  Af = (const float*)A;

  for (int kt = 0; kt < K; kt += 64) {
    if (afl == 0) {
#pragma unroll
      for (int r = 0; r < 4; ++r) {
        const int row = r * 32 + srow;
        *(bf16_8*)&As[row * 64 + scol] =
            *(const bf16_8*)(Ab + (size_t)(bm + row) * K + kt + scol);
      }
    } else {
#pragma unroll
      for (int r = 0; r < 4; ++r) {
        const int row = r * 32 + srow;
        const float* p = Af + (size_t)(bm + row) * K + kt + scol;
        bf16_8 v;
#pragma unroll
        for (int i = 0; i < 8; ++i) v[i] = (__bf16)p[i];
        *(bf16_8*)&As[row * 64 + scol] = v;
      }
    }
#pragma unroll
    for (int r = 0; r < 4; ++r) {
      const int row = r * 32 + srow;
      *(bf16_8*)&Bs[row * 64 + scol] =
          *(const bf16_8*)(Bt + (size_t)(bn + row) * K + kt + scol);
    }
    __syncthreads();
#pragma unroll
    for (int ks = 0; ks < 64; ks += 32) {
      bf16_8 af[4], bfv[4];
#pragma unroll
      for (int t = 0; t < 4; ++t)
        af[t] = *(const bf16_8*)(As + (wi + t * 16 + lrow) * 64 + ks + quad * 8);
#pragma unroll
      for (int t = 0; t < 4; ++t)
        bfv[t] = *(const bf16_8*)(Bs + (wn + t * 16 + lrow) * 64 + ks + quad * 8);
#pragma unroll
      for (int it = 0; it < 4; ++it)
#pragma unroll
        for (int nt = 0; nt < 4; ++nt)
          acc[it][nt] = __builtin_amdgcn_mfma_f32_16x16x32_bf16(
              af[it], bfv[nt], acc[it][nt], 0, 0, 0);
    }
    __syncthreads();
  }

  const int bfl = bflag[0];
  const int ofl = oflag[0];
#pragma unroll
  for (int nt = 0; nt < 4; ++nt) {
    const int c = bn + wn + nt * 16 + lrow;
    float bv = 0.0f;
    if (bias) {
      bv = (bfl == 0) ? (float)((const __bf16*)bias)[c]
                      : ((const float*)bias)[c];
    }
#pragma unroll
    for (int it = 0; it < 4; ++it) {
      const int rbase = bm + wi + it * 16 + quad * 4;
      if (ofl == 0) {
        __bf16* Cb = (__bf16*)C;
#pragma unroll
        for (int r = 0; r < 4; ++r)
          Cb[(size_t)(rbase + r) * N + c] = (__bf16)(acc[it][nt][r] + bv);
      } else {
        float* Cf = (float*)C;
#pragma unroll
        for (int r = 0; r < 4; ++r)
          Cf[(size_t)(rbase + r) * N + c] = acc[it][nt][r] + bv;
      }
    }
  }
}

// ---------------------------------------------------------------------------
// Flash attention.  Q,K: (B*2048, 512), head h at cols h*64..+63 (bf16, ws).
// Vt: (32, 64, 2048).  AO: (B*2048, 512).
// grid (2048/128, 32), block 256 (4 waves x 32 query rows).
__global__ __launch_bounds__(256) void attn_fwd(const __bf16* __restrict__ Q,
                                                const __bf16* __restrict__ Kb,
                                                const __bf16* __restrict__ Vt,
                                                __bf16* __restrict__ AO) {
  __shared__ __align__(16) __bf16 Pl[4][32 * 136];
  const int tid = threadIdx.x;
  const int lane = tid & 63;
  const int wave = tid >> 6;
  const int bh = blockIdx.y;
  const int b = bh >> 3, h = bh & 7;
  const int i0 = blockIdx.x * 128 + wave * 32;
  const int lrow = lane & 15;
  const int quad = lane >> 4;

  bf16_8 aq[2][2];
#pragma unroll
  for (int it = 0; it < 2; ++it)
#pragma unroll
    for (int ks = 0; ks < 2; ++ks)
      aq[it][ks] = *(const bf16_8*)(Q +
          (size_t)(b * 2048 + i0 + it * 16 + lrow) * 512 + h * 64 + ks * 32 + quad * 8);

  float mrow[2][4], lsum[2][4];
  f32_4 oacc[2][4];
#pragma unroll
  for (int it = 0; it < 2; ++it) {
#pragma unroll
    for (int r = 0; r < 4; ++r) { mrow[it][r] = -3.0e38f; lsum[it][r] = 0.0f; }
#pragma unroll
    for (int nt = 0; nt < 4; ++nt)
#pragma unroll
      for (int r = 0; r < 4; ++r) oacc[it][nt][r] = 0.0f;
  }

  __bf16* Pw = &Pl[wave][0];

  for (int jt = 0; jt < 16; ++jt) {
    const int j0 = jt * 128;
    f32_4 sacc[2][8];
#pragma unroll
    for (int it = 0; it < 2; ++it)
#pragma unroll
      for (int jn = 0; jn < 8; ++jn)
#pragma unroll
        for (int r = 0; r < 4; ++r) sacc[it][jn][r] = 0.0f;

    // S = Q K^T (128-key tile)
#pragma unroll
    for (int ks = 0; ks < 2; ++ks) {
      bf16_8 bk[8];
#pragma unroll
      for (int jn = 0; jn < 8; ++jn)
        bk[jn] = *(const bf16_8*)(Kb +
            (size_t)(b * 2048 + j0 + jn * 16 + lrow) * 512 + h * 64 + ks * 32 + quad * 8);
#pragma unroll
      for (int it = 0; it < 2; ++it)
#pragma unroll
        for (int jn = 0; jn < 8; ++jn)
          sacc[it][jn] = __builtin_amdgcn_mfma_f32_16x16x32_bf16(
              aq[it][ks], bk[jn], sacc[it][jn], 0, 0, 0);
    }

    // online softmax; rows (it, quad, r); cols (jn, lrow)
#pragma unroll
    for (int it = 0; it < 2; ++it) {
#pragma unroll
      for (int r = 0; r < 4; ++r) {
        float tmax = -3.0e38f;
#pragma unroll
        for (int jn = 0; jn < 8; ++jn) {
          sacc[it][jn][r] *= 0.125f;
          tmax = fmaxf(tmax, sacc[it][jn][r]);
        }
        tmax = fmaxf(tmax, __shfl_xor(tmax, 1));
        tmax = fmaxf(tmax, __shfl_xor(tmax, 2));
        tmax = fmaxf(tmax, __shfl_xor(tmax, 4));
        tmax = fmaxf(tmax, __shfl_xor(tmax, 8));
        const float mnew = fmaxf(mrow[it][r], tmax);
        const float alpha = __expf(mrow[it][r] - mnew);
        mrow[it][r] = mnew;
        float psum = 0.0f;
#pragma unroll
        for (int jn = 0; jn < 8; ++jn) {
          const float p = __expf(sacc[it][jn][r] - mnew);
          psum += p;
          Pw[(it * 16 + quad * 4 + r) * 136 + jn * 16 + lrow] = (__bf16)p;
        }
        psum += __shfl_xor(psum, 1);
        psum += __shfl_xor(psum, 2);
        psum += __shfl_xor(psum, 4);
        psum += __shfl_xor(psum, 8);
        lsum[it][r] = lsum[it][r] * alpha + psum;
#pragma unroll
        for (int nt = 0; nt < 4; ++nt) oacc[it][nt][r] *= alpha;
      }
    }

    __syncthreads();  // P writes ordered before A-layout reads

    // O += P V
#pragma unroll
    for (int ks2 = 0; ks2 < 4; ++ks2) {
      bf16_8 ap[2], bv[4];
#pragma unroll
      for (int it = 0; it < 2; ++it)
        ap[it] = *(const bf16_8*)(Pw + (it * 16 + lrow) * 136 + ks2 * 32 + quad * 8);
#pragma unroll
      for (int nt = 0; nt < 4; ++nt)
        bv[nt] = *(const bf16_8*)(Vt +
            (size_t)(bh * 64 + nt * 16 + lrow) * 2048 + j0 + ks2 * 32 + quad * 8);
#pragma unroll
      for (int it = 0; it < 2; ++it)
#pragma unroll
        for (int nt = 0; nt < 4; ++nt)
          oacc[it][nt] = __builtin_amdgcn_mfma_f32_16x16x32_bf16(
              ap[it], bv[nt], oacc[it][nt], 0, 0, 0);
    }

    __syncthreads();  // P reads done before next tile's writes
  }

#pragma unroll
  for (int it = 0; it < 2; ++it) {
#pragma unroll
    for (int r = 0; r < 4; ++r) {
      const float inv = 1.0f / lsum[it][r];
      const size_t rg = (size_t)(b * 2048 + i0 + it * 16 + quad * 4 + r);
#pragma unroll
      for (int nt = 0; nt < 4; ++nt)
        AO[rg * 512 + h * 64 + nt * 16 + lrow] = (__bf16)(oacc[it][nt][r] * inv);
    }
  }
}

// ---------------------------------------------------------------------------
extern "C" void kernel_launch(void* const* d_in, const int* in_sizes, int n_in,
                              void* d_out, int out_size, void* d_ws, size_t ws_size,
                              hipStream_t stream) {
  (void)in_sizes; (void)n_in; (void)out_size; (void)ws_size;
  const void* x   = d_in[0];  // (4,2048,1024)
  const void* ctx = d_in[1];  // (4,2048,768)
  const void* Wq  = d_in[2];  // (1024,512)
  const void* Wk  = d_in[3];  // (768,512)
  const void* Wv  = d_in[4];  // (768,512)
  const void* Wo  = d_in[5];  // (512,1024)
  const void* bo  = d_in[6];  // (1024,)

  char* wsb = (char*)d_ws;
  int* flags = (int*)wsb;                          // [0]=io dtype, [1]=0
  __bf16* WqT  = (__bf16*)(wsb + 64);              // 512*1024
  __bf16* WkT  = WqT + 512 * 1024;                 // 512*768
  __bf16* WvT  = WkT + 512 * 768;                  // 512*768
  __bf16* WoT  = WvT + 512 * 768;                  // 1024*512
  __bf16* Qb   = WoT + 1024 * 512;                 // 8192*512
  __bf16* Kbuf = Qb + 8192 * 512;                  // 8192*512
  __bf16* Vbuf = Kbuf + 8192 * 512;                // 8192*512
  __bf16* Vtb  = Vbuf + 8192 * 512;                // 32*64*2048
  __bf16* AOb  = Vtb + 8192 * 512;                 // 8192*512

  sniff_dtype<<<1, 64, 0, stream>>>((const unsigned short*)x, flags);

  transpose_w<<<dim3(512 / 32, 1024 / 32), 256, 0, stream>>>(Wq, WqT, 1024, 512, flags);
  transpose_w<<<dim3(512 / 32, 768 / 32), 256, 0, stream>>>(Wk, WkT, 768, 512, flags);
  transpose_w<<<dim3(512 / 32, 768 / 32), 256, 0, stream>>>(Wv, WvT, 768, 512, flags);
  transpose_w<<<dim3(1024 / 32, 512 / 32), 256, 0, stream>>>(Wo, WoT, 512, 1024, flags);

  gemm_bt<<<dim3(4, 64), 256, 0, stream>>>(x,   WqT, Qb,   8192, 512, 1024, nullptr, flags, flags + 1, flags + 1);
  gemm_bt<<<dim3(4, 64), 256, 0, stream>>>(ctx, WkT, Kbuf, 8192, 512, 768,  nullptr, flags, flags + 1, flags + 1);
  gemm_bt<<<dim3(4, 64), 256, 0, stream>>>(ctx, WvT, Vbuf, 8192, 512, 768,  nullptr, flags, flags + 1, flags + 1);

  transpose_v<<<dim3(32, 32), 256, 0, stream>>>(Vbuf, Vtb);

  attn_fwd<<<dim3(16, 32), 256, 0, stream>>>(Qb, Kbuf, Vtb, AOb);

  // output GEMM: A=AO (bf16), bias dtype = input dtype, OUT dtype = input dtype
  gemm_bt<<<dim3(8, 64), 256, 0, stream>>>(AOb, WoT, d_out, 8192, 1024, 512, bo, flags + 1, flags, flags);
}